// Round 1
// baseline (354.142 us; speedup 1.0000x reference)
//
#include <hip/hip_runtime.h>

typedef unsigned short u16;
typedef __attribute__((ext_vector_type(8))) short s16x8;   // 8 x bf16 frag (verified form)
typedef __attribute__((ext_vector_type(4))) float floatx4;

// xt (per batch): [cg=16][row=66][col=66][c32=32] bf16, spatial-padded NCHW32c
// SWIZZLED: within each 64B (row,col) channel-group, c32 index ^= ((col>>1)&3)<<3
#define XT_ROWELEMS 2112                 // 66*32
#define XT_CGELEMS  139392               // 66*66*32
#define XT_PB       4460544ull           // 16*66*66*32*2 bytes per batch
// wmod (per batch): [og=4][t=9][cg=16][o128=128][c32=32] bf16
// SWIZZLED: within each 64B o128-row, c32 index ^= ((o128>>1)&3)<<3
#define WM_PB       4718592ull           // 4*9*16*128*32*2 bytes per batch

// async global->LDS DMA, 16B per lane; lds dest = wave-uniform base + lane*16
#define GLDS(gp, lp) __builtin_amdgcn_global_load_lds(                      \
    (const __attribute__((address_space(1))) void*)(gp),                    \
    (__attribute__((address_space(3))) void*)(lp), 16, 0, 0)

// counted vmcnt + raw barrier (memory clobber keeps LDS reads from hoisting)
#define WAITVM(N) asm volatile("s_waitcnt vmcnt(" #N ")" ::: "memory")
#define SBAR()    asm volatile("s_barrier" ::: "memory")

__device__ __forceinline__ u16 f2bf(float f) {
  union { float f; unsigned u; } x; x.f = f;
  unsigned r = x.u + 0x7fffu + ((x.u >> 16) & 1u);
  return (u16)(r >> 16);
}

// ---------------- kernel 1: fp32 NCHW -> padded NCHW32c bf16 (pre-swizzled) ----------------
// grid (64, 16, nb), 256 threads. Zeroes its own halo (zeros are swizzle-invariant).
__global__ __launch_bounds__(256) void transpose_nchw32(
    const float* __restrict__ fm, u16* __restrict__ xt, int b0)
{
  const int y = blockIdx.x, cg = blockIdx.y, bl = blockIdx.z, tid = threadIdx.x;
  __shared__ float sm[64 * 33];
  const int x = tid & 63, cq = tid >> 6;
  const float* src = fm + (((size_t)(b0 + bl) * 512 + cg * 32) * 64 + y) * 64;
#pragma unroll
  for (int j = 0; j < 8; ++j) {
    int ci = j * 4 + cq;
    sm[x * 33 + ci] = src[(size_t)ci * 4096 + x];   // coalesced along x
  }

  u16* cgbase = xt + (size_t)(bl * 16 + cg) * XT_CGELEMS;
  const uint4 z = {0u, 0u, 0u, 0u};
  u16* rowb = cgbase + (size_t)(y + 1) * XT_ROWELEMS;
  if (tid < 4)              ((uint4*)rowb)[tid] = z;                  // col 0
  else if (tid < 8)         ((uint4*)(rowb + 65 * 32))[tid - 4] = z;  // col 65
  if (y == 0)  for (int i = tid; i < 264; i += 256) ((uint4*)cgbase)[i] = z;
  if (y == 63) for (int i = tid; i < 264; i += 256) ((uint4*)(cgbase + 65 * XT_ROWELEMS))[i] = z;

  __syncthreads();
  // interior cols 1..64: each thread writes one 16B slot = channels (tid&3)*8..+7
  // of col 1+(tid>>2). Pre-swizzle: slot ^= (col>>1)&3.
  union { u16 s[8]; uint4 v; } u;
#pragma unroll
  for (int j = 0; j < 8; ++j) {
    int e = tid * 8 + j;                            // e = x*32 + c32
    u.s[j] = f2bf(sm[(e >> 5) * 33 + (e & 31)]);
  }
  const int col = 1 + (tid >> 2);
  const int slot = (tid & 3) ^ ((col >> 1) & 3);
  ((uint4*)rowb)[col * 4 + slot] = u.v;
}

// ---------------- kernel 2: modulate + demodulate weights (pre-swizzled) ----------------
// grid (512, nb), 256 threads.
__global__ __launch_bounds__(256) void modulate(
    const float* __restrict__ w, const float* __restrict__ style,
    u16* __restrict__ wm, int b0)
{
  const int o = blockIdx.x, bl = blockIdx.y, tid = threadIdx.x;
  __shared__ float sv[4608];
  __shared__ float red[4];
  const float gain = 0.014731391f;                  // 1/sqrt(512*9)
  const float* wo = w + (size_t)o * 4608;           // flat idx = ci*9 + t
  const float* st = style + (size_t)(b0 + bl) * 512;
  float ss = 0.f;
#pragma unroll
  for (int j = 0; j < 18; ++j) {
    int idx = j * 256 + tid;
    float v = wo[idx] * gain * st[idx / 9];
    sv[idx] = v;
    ss += v * v;
  }
#pragma unroll
  for (int off = 32; off > 0; off >>= 1) ss += __shfl_down(ss, off, 64);
  if ((tid & 63) == 0) red[tid >> 6] = ss;
  __syncthreads();
  float sinv = rsqrtf(red[0] + red[1] + red[2] + red[3] + 1e-8f);
  const int og = o >> 7, o128 = o & 127;
  const int axor = ((o128 >> 1) & 3) << 3;          // pre-swizzle for conv A-reads
  u16* base = wm + ((size_t)((bl * 4 + og) * 9) * 16 * 128 + o128) * 32;
#pragma unroll
  for (int j = 0; j < 18; ++j) {
    int e = j * 256 + tid;                          // e = t*512 + c
    int t = e >> 9, c = e & 511;
    base[((size_t)(t * 16 + (c >> 5))) * 4096 + ((c & 31) ^ axor)] = f2bf(sv[c * 9 + t] * sinv);
  }
}

// ---------------- kernel 3: implicit-GEMM conv via bf16 MFMA ----------------
// grid 32*4*nb linear, 256 threads. C[o,p] 128x128 per block, K=4608.
// Depth-3 A-pipeline (4 bufs) with counted vmcnt; single Bs restaged per cg
// (full drain only at the 16 cg boundaries). LDS reads XOR-swizzled (2-way, free).
__global__ __launch_bounds__(256, 3) void conv_mfma(
    const u16* __restrict__ Wmod, const u16* __restrict__ xt,
    float* __restrict__ out, int b0, int nb)
{
  const int id = blockIdx.x;
  const int bl = id % nb;                           // same batch -> same XCD (round robin)
  const int rest = id / nb;
  const int og = rest & 3, p_blk = rest >> 2;
  const int tid = threadIdx.x;
  const int lane = tid & 63, wave = tid >> 6;
  const int wm_off = (wave & 1) * 64, wn_off = (wave >> 1) * 64;
  const int l15 = lane & 15, quad = lane >> 4;

  __shared__ __align__(16) u16 As[4][4096];         // 4 x 8 KB A k-slices
  __shared__ __align__(16) u16 Bs[8448];            // [r4][col66][c32] = 16896 B

  const int y0 = p_blk * 2;
  const size_t xt_base = ((size_t)(bl * 16) * XT_CGELEMS) + (size_t)y0 * XT_ROWELEMS;
  const size_t w_base = (size_t)((bl * 4 + og) * 9) * 16 * 4096;

  auto stage_b = [&](int cg) {                      // 16896 B contiguous, async
    const char* g = (const char*)(xt + xt_base + (size_t)cg * XT_CGELEMS);
    for (int r = wave; r < 16; r += 4)
      GLDS(g + r * 1024 + lane * 16, (char*)Bs + r * 1024);
    if (wave == 0 && lane < 32)                     // 512 B tail
      GLDS(g + 16384 + lane * 16, (char*)Bs + 16384);
  };
  auto stage_a = [&](int t, int cg, int buf) {      // 8192 B contiguous, async (2 GLDS/wave)
    const char* g = (const char*)(Wmod + w_base + (size_t)(t * 16 + cg) * 4096);
    for (int r = wave; r < 8; r += 4)
      GLDS(g + r * 1024 + lane * 16, (char*)As[buf] + r * 1024);
  };

  // loop-invariant swizzled fragment addresses
  int aoff[4];
#pragma unroll
  for (int mt = 0; mt < 4; ++mt) {
    int row = wm_off + mt * 16 + l15;               // o128 row, lanes step rows
    aoff[mt] = row * 32 + ((quad ^ ((row >> 1) & 3)) << 3);
  }
  int pr[4], pc[4];
#pragma unroll
  for (int nt = 0; nt < 4; ++nt) {
    int p = wn_off + nt * 16 + l15;
    pr[nt] = p >> 6; pc[nt] = p & 63;
  }

  floatx4 acc[4][4];
  const floatx4 zf = {0.f, 0.f, 0.f, 0.f};
#pragma unroll
  for (int mt = 0; mt < 4; ++mt)
#pragma unroll
    for (int nt = 0; nt < 4; ++nt) acc[mt][nt] = zf;

  // prologue: B(cg0) + A(s=0,1,2); full drain once
  stage_b(0);
  stage_a(0, 0, 0);
  stage_a(1, 0, 1);
  stage_a(2, 0, 2);
  __syncthreads();

#pragma unroll 1
  for (int cg = 0; cg < 16; ++cg) {
#pragma unroll
    for (int t = 0; t < 9; ++t) {
      const int s = cg * 9 + t;
      const int cur = s & 3;
      // top-of-step wait: own A(s) landed (and B at cg start); then sync all waves.
      // steady state keeps A(s+1), A(s+2) in flight (never drain to 0 mid-cg).
      if (t == 0)         WAITVM(0);                // B(cg) is newest in FIFO
      else if (s <= 141)  WAITVM(2);
      else if (s == 142)  WAITVM(1);                // tail: fewer prefetches in flight
      else                WAITVM(0);
      SBAR();
      // prefetch A for step s+3 into buffer last read at s-1 (reads closed by barrier above)
      if (s + 3 < 144) {
        int t3 = t + 3, cg3 = cg;
        if (t3 >= 9) { t3 -= 9; ++cg3; }
        stage_a(t3, cg3, (s + 3) & 3);
      }

      const int ky = t / 3, kx = t - ky * 3;
      s16x8 afr[4], bfr[4];
      const u16* Ab = As[cur];
#pragma unroll
      for (int mt = 0; mt < 4; ++mt)                // A[m=lane&15][k=quad*8+j], swizzled
        afr[mt] = *(const s16x8*)&Ab[aoff[mt]];
#pragma unroll
      for (int nt = 0; nt < 4; ++nt) {              // B[n=lane&15][k=quad*8+j], swizzled
        int r = pr[nt] + ky, c = pc[nt] + kx;
        bfr[nt] = *(const s16x8*)&Bs[(r * 66 + c) * 32 + ((quad ^ ((c >> 1) & 3)) << 3)];
      }
      __builtin_amdgcn_s_setprio(1);
#pragma unroll
      for (int mt = 0; mt < 4; ++mt)
#pragma unroll
        for (int nt = 0; nt < 4; ++nt)
          acc[mt][nt] = __builtin_amdgcn_mfma_f32_16x16x32_bf16(
              afr[mt], bfr[nt], acc[mt][nt], 0, 0, 0);
      __builtin_amdgcn_s_setprio(0);

      if (t == 8 && cg < 15) {                      // cg boundary: restage Bs
        asm volatile("s_waitcnt lgkmcnt(0)" ::: "memory");
        SBAR();                                     // all waves done reading Bs
        stage_b(cg + 1);                            // async; drained at next t==0
      }
    }
  }

  // epilogue: C/D layout col=lane&15, row=quad*4+reg (m89-verified)
  float* outp = out + ((size_t)(b0 + bl) * 512 + og * 128) * 4096 + p_blk * 128;
#pragma unroll
  for (int mt = 0; mt < 4; ++mt)
#pragma unroll
    for (int nt = 0; nt < 4; ++nt) {
      int n = wn_off + nt * 16 + l15;
#pragma unroll
      for (int r = 0; r < 4; ++r) {
        int m = wm_off + mt * 16 + quad * 4 + r;
        outp[(size_t)m * 4096 + n] = acc[mt][nt][r];
      }
    }
}

// ---------------- fallback: zero-workspace direct conv (R6, known-PASS) ----------------
__global__ __launch_bounds__(256) void conv_direct(
    const float* __restrict__ fm, const float* __restrict__ style,
    const float* __restrict__ w, float* __restrict__ out)
{
  const int o = blockIdx.x, b = blockIdx.y, tid = threadIdx.x;
  __shared__ float swm[4608];
  __shared__ float red[4];
  const float gain = 0.014731391f;
  const float* wo = w + (size_t)o * 4608;
  const float* st = style + (size_t)b * 512;
  float ss = 0.f;
#pragma unroll
  for (int j = 0; j < 18; ++j) {
    int idx = j * 256 + tid;
    float v = wo[idx] * gain * st[idx / 9];
    swm[idx] = v;
    ss += v * v;
  }
#pragma unroll
  for (int off = 32; off > 0; off >>= 1) ss += __shfl_down(ss, off, 64);
  if ((tid & 63) == 0) red[tid >> 6] = ss;
  __syncthreads();
  const float sinv = rsqrtf(red[0] + red[1] + red[2] + red[3] + 1e-8f);

  const int y = tid >> 2, x0 = (tid & 3) * 16;
  float acc[16];
#pragma unroll
  for (int i = 0; i < 16; ++i) acc[i] = 0.f;
  const float* fb = fm + (size_t)b * 512 * 4096;
  for (int ci = 0; ci < 512; ++ci) {
    const float* fc = fb + (size_t)ci * 4096;
    const float* wr = swm + ci * 9;
#pragma unroll
    for (int ky = 0; ky < 3; ++ky) {
      int yy = y + ky - 1;
      if (yy < 0 || yy > 63) continue;
      const float* frow = fc + yy * 64;
#pragma unroll
      for (int kx = 0; kx < 3; ++kx) {
        float wv = wr[ky * 3 + kx];
#pragma unroll
        for (int i = 0; i < 16; ++i) {
          int xx = x0 + i + kx - 1;
          float xv = (xx >= 0 && xx < 64) ? frow[xx] : 0.f;
          acc[i] += wv * xv;
        }
      }
    }
  }
  float* op = out + ((size_t)b * 512 + o) * 4096 + y * 64 + x0;
#pragma unroll
  for (int i = 0; i < 16; ++i) op[i] = acc[i] * sinv;
}

extern "C" void kernel_launch(void* const* d_in, const int* in_sizes, int n_in,
                              void* d_out, int out_size, void* d_ws, size_t ws_size,
                              hipStream_t stream) {
  const float* fm = (const float*)d_in[0];     // (8,512,64,64) fp32
  const float* style = (const float*)d_in[1];  // (8,512) fp32
  const float* w = (const float*)d_in[2];      // (512,512,3,3) fp32
  float* out = (float*)d_out;                  // (8,512,64,64) fp32

  if (ws_size < XT_PB + WM_PB) {               // workspace too small: direct path
    conv_direct<<<dim3(512, 8), 256, 0, stream>>>(fm, style, w, out);
    return;
  }
  int nb = 8;
  while (nb > 1 && (size_t)nb * (XT_PB + WM_PB) > ws_size) nb >>= 1;

  u16* xt = (u16*)d_ws;
  u16* wmod = (u16*)((char*)d_ws + (size_t)nb * XT_PB);

  for (int b0 = 0; b0 < 8; b0 += nb) {
    transpose_nchw32<<<dim3(64, 16, nb), 256, 0, stream>>>(fm, xt, b0);
    modulate<<<dim3(512, nb), 256, 0, stream>>>(w, style, wmod, b0);
    conv_mfma<<<dim3(32 * 4 * nb), 256, 0, stream>>>(wmod, xt, out, b0, nb);
  }
}

// Round 2
// 274.454 us; speedup vs baseline: 1.2904x; 1.2904x over previous
//
#include <hip/hip_runtime.h>

typedef unsigned short u16;
typedef __attribute__((ext_vector_type(8))) short s16x8;   // 8 x bf16 frag (verified form)
typedef __attribute__((ext_vector_type(4))) float floatx4;

// xt (per batch): [cg=16][row=66][col=66][c32=32] bf16, spatial-padded NCHW32c
// SWIZZLED: within each 64B (row,col) channel-group, c32 index ^= ((col>>1)&3)<<3
#define XT_ROWELEMS 2112                 // 66*32
#define XT_CGELEMS  139392               // 66*66*32
#define XT_PB       4460544ull           // 16*66*66*32*2 bytes per batch
// wmod (per batch): [t=9][cg=16][o512=512][c32=32] bf16  (o512 contiguous for M=256 tiles)
// SWIZZLED: within each 64B o-row, c32 index ^= ((o>>1)&3)<<3
#define WM_ELEMS    2359296ull           // 9*16*512*32 elems per batch
#define WM_PB       4718592ull           // bytes per batch

// async global->LDS DMA, 16B per lane; lds dest = wave-uniform base + lane*16
#define GLDS(gp, lp) __builtin_amdgcn_global_load_lds(                      \
    (const __attribute__((address_space(1))) void*)(gp),                    \
    (__attribute__((address_space(3))) void*)(lp), 16, 0, 0)

__device__ __forceinline__ u16 f2bf(float f) {
  union { float f; unsigned u; } x; x.f = f;
  unsigned r = x.u + 0x7fffu + ((x.u >> 16) & 1u);
  return (u16)(r >> 16);
}

// ---------------- kernel 1: fp32 NCHW -> padded NCHW32c bf16 (pre-swizzled) ----------------
// grid (64, 16, nb), 256 threads. Zeroes its own halo (zeros are swizzle-invariant).
__global__ __launch_bounds__(256) void transpose_nchw32(
    const float* __restrict__ fm, u16* __restrict__ xt, int b0)
{
  const int y = blockIdx.x, cg = blockIdx.y, bl = blockIdx.z, tid = threadIdx.x;
  __shared__ float sm[64 * 33];
  const int x = tid & 63, cq = tid >> 6;
  const float* src = fm + (((size_t)(b0 + bl) * 512 + cg * 32) * 64 + y) * 64;
#pragma unroll
  for (int j = 0; j < 8; ++j) {
    int ci = j * 4 + cq;
    sm[x * 33 + ci] = src[(size_t)ci * 4096 + x];   // coalesced along x
  }

  u16* cgbase = xt + (size_t)(bl * 16 + cg) * XT_CGELEMS;
  const uint4 z = {0u, 0u, 0u, 0u};
  u16* rowb = cgbase + (size_t)(y + 1) * XT_ROWELEMS;
  if (tid < 4)              ((uint4*)rowb)[tid] = z;                  // col 0
  else if (tid < 8)         ((uint4*)(rowb + 65 * 32))[tid - 4] = z;  // col 65
  if (y == 0)  for (int i = tid; i < 264; i += 256) ((uint4*)cgbase)[i] = z;
  if (y == 63) for (int i = tid; i < 264; i += 256) ((uint4*)(cgbase + 65 * XT_ROWELEMS))[i] = z;

  __syncthreads();
  // interior cols 1..64: thread writes one 16B slot = channels (tid&3)*8..+7
  // of col 1+(tid>>2). Pre-swizzle: slot ^= (col>>1)&3.
  union { u16 s[8]; uint4 v; } u;
#pragma unroll
  for (int j = 0; j < 8; ++j) {
    int e = tid * 8 + j;                            // e = x*32 + c32
    u.s[j] = f2bf(sm[(e >> 5) * 33 + (e & 31)]);
  }
  const int col = 1 + (tid >> 2);
  const int slot = (tid & 3) ^ ((col >> 1) & 3);
  ((uint4*)rowb)[col * 4 + slot] = u.v;
}

// ---------------- kernel 2: modulate + demodulate weights (pre-swizzled, o512 layout) ----------------
// grid (512, nb), 256 threads.
__global__ __launch_bounds__(256) void modulate(
    const float* __restrict__ w, const float* __restrict__ style,
    u16* __restrict__ wm, int b0)
{
  const int o = blockIdx.x, bl = blockIdx.y, tid = threadIdx.x;
  __shared__ float sv[4608];
  __shared__ float red[4];
  const float gain = 0.014731391f;                  // 1/sqrt(512*9)
  const float* wo = w + (size_t)o * 4608;           // flat idx = ci*9 + t
  const float* st = style + (size_t)(b0 + bl) * 512;
  float ss = 0.f;
#pragma unroll
  for (int j = 0; j < 18; ++j) {
    int idx = j * 256 + tid;
    float v = wo[idx] * gain * st[idx / 9];
    sv[idx] = v;
    ss += v * v;
  }
#pragma unroll
  for (int off = 32; off > 0; off >>= 1) ss += __shfl_down(ss, off, 64);
  if ((tid & 63) == 0) red[tid >> 6] = ss;
  __syncthreads();
  float sinv = rsqrtf(red[0] + red[1] + red[2] + red[3] + 1e-8f);
  const int axor = ((o >> 1) & 3) << 3;             // pre-swizzle for conv A-reads
  u16* base = wm + (size_t)bl * WM_ELEMS + (size_t)o * 32;
#pragma unroll
  for (int j = 0; j < 18; ++j) {
    int e = j * 256 + tid;                          // e = t*512 + c
    int t = e >> 9, c = e & 511;
    base[((size_t)(t * 16 + (c >> 5))) * 16384 + ((c & 31) ^ axor)] = f2bf(sv[c * 9 + t] * sinv);
  }
}

// ---------------- kernel 3: implicit-GEMM conv via bf16 MFMA ----------------
// grid 64*nb linear, 256 threads. C tile 256x128 per block, K=4608.
// Wave tile 128x64 (8x4 frags): 12 ds_read_b128 per 32 MFMA (ratio 2.67) ->
// LDS-read no longer the binding resource. Proven m97-style sync discipline
// (stage next A async, __syncthreads per K-step drains DMA). Swizzled LDS
// reads (conflicts = 0, verified round 1).
__global__ __launch_bounds__(256, 2) void conv_mfma(
    const u16* __restrict__ Wmod, const u16* __restrict__ xt,
    float* __restrict__ out, int b0, int nb)
{
  const int id = blockIdx.x;
  const int bl = id % nb;                           // same batch -> same XCD (round robin)
  const int rest = id / nb;
  const int og = rest & 1, p_blk = rest >> 1;       // og: 256-row M chunk
  const int tid = threadIdx.x;
  const int lane = tid & 63, wave = tid >> 6;
  const int wm_off = (wave & 1) * 128, wn_off = (wave >> 1) * 64;
  const int l15 = lane & 15, quad = lane >> 4;

  __shared__ __align__(16) u16 As[2][8192];         // 2 x 16 KB A k-slices (256 rows x 32)
  __shared__ __align__(16) u16 Bs[8448];            // [r4][col66][c32] = 16896 B

  const int y0 = p_blk * 2;
  const size_t xt_base = ((size_t)(bl * 16) * XT_CGELEMS) + (size_t)y0 * XT_ROWELEMS;
  const size_t w_base = (size_t)bl * WM_ELEMS + (size_t)og * (256 * 32);

  auto stage_b = [&](int cg) {                      // 16896 B contiguous, async
    const char* g = (const char*)(xt + xt_base + (size_t)cg * XT_CGELEMS);
    for (int r = wave; r < 16; r += 4)
      GLDS(g + r * 1024 + lane * 16, (char*)Bs + r * 1024);
    if (wave == 0 && lane < 32)                     // 512 B tail
      GLDS(g + 16384 + lane * 16, (char*)Bs + 16384);
  };
  auto stage_a = [&](int t, int cg, int buf) {      // 16 KB contiguous, async (4 GLDS/thread)
    const char* g = (const char*)(Wmod + w_base + (size_t)(t * 16 + cg) * 16384);
    for (int r = wave; r < 16; r += 4)
      GLDS(g + r * 1024 + lane * 16, (char*)As[buf] + r * 1024);
  };

  // loop-invariant swizzled fragment addresses
  int aoff[8];
#pragma unroll
  for (int mt = 0; mt < 8; ++mt) {
    int row = wm_off + mt * 16 + l15;               // local o-row; global o = og*256+row,
    aoff[mt] = row * 32 + ((quad ^ ((row >> 1) & 3)) << 3);  // same ((o>>1)&3) swizzle
  }
  int pr[4], pc[4];
#pragma unroll
  for (int nt = 0; nt < 4; ++nt) {
    int p = wn_off + nt * 16 + l15;
    pr[nt] = p >> 6; pc[nt] = p & 63;
  }

  floatx4 acc[8][4];
  const floatx4 zf = {0.f, 0.f, 0.f, 0.f};
#pragma unroll
  for (int mt = 0; mt < 8; ++mt)
#pragma unroll
    for (int nt = 0; nt < 4; ++nt) acc[mt][nt] = zf;

  stage_b(0);
  stage_a(0, 0, 0);
  __syncthreads();                                  // vmcnt drain -> data visible

#pragma unroll 1
  for (int cg = 0; cg < 16; ++cg) {
#pragma unroll 1
    for (int t = 0; t < 9; ++t) {
      const int cur = (cg * 9 + t) & 1, nxt = cur ^ 1;
      const bool last = (cg == 15 && t == 8);
      const bool cgb = (t == 8 && cg < 15);         // cg boundary
      if (!last) stage_a(t < 8 ? t + 1 : 0, t < 8 ? cg : cg + 1, nxt);  // async prefetch

      const int ky = t / 3, kx = t - ky * 3;
      s16x8 afr[8], bfr[4];
      const u16* Ab = As[cur];
#pragma unroll
      for (int nt = 0; nt < 4; ++nt) {              // B[n=lane&15][k=quad*8+j], swizzled
        int r = pr[nt] + ky, c = pc[nt] + kx;
        bfr[nt] = *(const s16x8*)&Bs[(r * 66 + c) * 32 + ((quad ^ ((c >> 1) & 3)) << 3)];
      }
#pragma unroll
      for (int mt = 0; mt < 8; ++mt)                // A[m=lane&15][k=quad*8+j], swizzled
        afr[mt] = *(const s16x8*)&Ab[aoff[mt]];
#pragma unroll
      for (int mt = 0; mt < 8; ++mt)
#pragma unroll
        for (int nt = 0; nt < 4; ++nt)
          acc[mt][nt] = __builtin_amdgcn_mfma_f32_16x16x32_bf16(
              afr[mt], bfr[nt], acc[mt][nt], 0, 0, 0);

      if (cgb) {
        __syncthreads();                            // all waves done reading Bs
        stage_b(cg + 1);                            // async restage
      }
      __syncthreads();                              // drains DMA; LDS visible
    }
  }

  // epilogue: C/D layout col=lane&15, row=quad*4+reg (m89-verified)
  float* outp = out + ((size_t)(b0 + bl) * 512 + og * 256) * 4096 + p_blk * 128;
#pragma unroll
  for (int mt = 0; mt < 8; ++mt)
#pragma unroll
    for (int nt = 0; nt < 4; ++nt) {
      int n = wn_off + nt * 16 + l15;
#pragma unroll
      for (int r = 0; r < 4; ++r) {
        int m = wm_off + mt * 16 + quad * 4 + r;
        outp[(size_t)m * 4096 + n] = acc[mt][nt][r];
      }
    }
}

// ---------------- fallback: zero-workspace direct conv (R6, known-PASS) ----------------
__global__ __launch_bounds__(256) void conv_direct(
    const float* __restrict__ fm, const float* __restrict__ style,
    const float* __restrict__ w, float* __restrict__ out)
{
  const int o = blockIdx.x, b = blockIdx.y, tid = threadIdx.x;
  __shared__ float swm[4608];
  __shared__ float red[4];
  const float gain = 0.014731391f;
  const float* wo = w + (size_t)o * 4608;
  const float* st = style + (size_t)b * 512;
  float ss = 0.f;
#pragma unroll
  for (int j = 0; j < 18; ++j) {
    int idx = j * 256 + tid;
    float v = wo[idx] * gain * st[idx / 9];
    swm[idx] = v;
    ss += v * v;
  }
#pragma unroll
  for (int off = 32; off > 0; off >>= 1) ss += __shfl_down(ss, off, 64);
  if ((tid & 63) == 0) red[tid >> 6] = ss;
  __syncthreads();
  const float sinv = rsqrtf(red[0] + red[1] + red[2] + red[3] + 1e-8f);

  const int y = tid >> 2, x0 = (tid & 3) * 16;
  float acc[16];
#pragma unroll
  for (int i = 0; i < 16; ++i) acc[i] = 0.f;
  const float* fb = fm + (size_t)b * 512 * 4096;
  for (int ci = 0; ci < 512; ++ci) {
    const float* fc = fb + (size_t)ci * 4096;
    const float* wr = swm + ci * 9;
#pragma unroll
    for (int ky = 0; ky < 3; ++ky) {
      int yy = y + ky - 1;
      if (yy < 0 || yy > 63) continue;
      const float* frow = fc + yy * 64;
#pragma unroll
      for (int kx = 0; kx < 3; ++kx) {
        float wv = wr[ky * 3 + kx];
#pragma unroll
        for (int i = 0; i < 16; ++i) {
          int xx = x0 + i + kx - 1;
          float xv = (xx >= 0 && xx < 64) ? frow[xx] : 0.f;
          acc[i] += wv * xv;
        }
      }
    }
  }
  float* op = out + ((size_t)b * 512 + o) * 4096 + y * 64 + x0;
#pragma unroll
  for (int i = 0; i < 16; ++i) op[i] = acc[i] * sinv;
}

extern "C" void kernel_launch(void* const* d_in, const int* in_sizes, int n_in,
                              void* d_out, int out_size, void* d_ws, size_t ws_size,
                              hipStream_t stream) {
  const float* fm = (const float*)d_in[0];     // (8,512,64,64) fp32
  const float* style = (const float*)d_in[1];  // (8,512) fp32
  const float* w = (const float*)d_in[2];      // (512,512,3,3) fp32
  float* out = (float*)d_out;                  // (8,512,64,64) fp32

  if (ws_size < XT_PB + WM_PB) {               // workspace too small: direct path
    conv_direct<<<dim3(512, 8), 256, 0, stream>>>(fm, style, w, out);
    return;
  }
  int nb = 8;
  while (nb > 1 && (size_t)nb * (XT_PB + WM_PB) > ws_size) nb >>= 1;

  u16* xt = (u16*)d_ws;
  u16* wmod = (u16*)((char*)d_ws + (size_t)nb * XT_PB);

  for (int b0 = 0; b0 < 8; b0 += nb) {
    transpose_nchw32<<<dim3(64, 16, nb), 256, 0, stream>>>(fm, xt, b0);
    modulate<<<dim3(512, nb), 256, 0, stream>>>(w, style, wmod, b0);
    conv_mfma<<<dim3(64 * nb), 256, 0, stream>>>(wmod, xt, out, b0, nb);
  }
}

// Round 3
// 267.970 us; speedup vs baseline: 1.3216x; 1.0242x over previous
//
#include <hip/hip_runtime.h>

typedef unsigned short u16;
typedef __attribute__((ext_vector_type(8))) short s16x8;   // 8 x bf16 frag (verified form)
typedef __attribute__((ext_vector_type(4))) float floatx4;

// xt (per batch): [cg=16][row=66][col=66][c32=32] bf16, spatial-padded NCHW32c
// SWIZZLED: within each 64B (row,col) channel-group, c32 index ^= ((col>>1)&3)<<3
#define XT_ROWELEMS 2112                 // 66*32
#define XT_CGELEMS  139392               // 66*66*32
#define XT_PB       4460544ull           // 16*66*66*32*2 bytes per batch
// wmod (per batch): [t=9][cg=16][o512=512][c32=32] bf16  (o512 contiguous for M=256 tiles)
// SWIZZLED: within each 64B o-row, c32 index ^= ((o>>1)&3)<<3
#define WM_ELEMS    2359296ull           // 9*16*512*32 elems per batch
#define WM_PB       4718592ull           // bytes per batch

// async global->LDS DMA, 16B per lane; lds dest = wave-uniform base + lane*16
#define GLDS(gp, lp) __builtin_amdgcn_global_load_lds(                      \
    (const __attribute__((address_space(1))) void*)(gp),                    \
    (__attribute__((address_space(3))) void*)(lp), 16, 0, 0)

__device__ __forceinline__ u16 f2bf(float f) {
  union { float f; unsigned u; } x; x.f = f;
  unsigned r = x.u + 0x7fffu + ((x.u >> 16) & 1u);
  return (u16)(r >> 16);
}

// ---------------- fused producer: transpose + modulate in one dispatch ----------------
// grid (1536*nb), 256 threads. Block roles interleaved for co-residency:
//   bid%3 < 2  -> transpose tile ti = (bid/3)*2 + bid%3   (1024*nb tiles)
//   bid%3 == 2 -> modulate row  mi = bid/3                (512*nb rows)
// transpose is memory-bound, modulate is VALU-bound (f2bf + div) -> overlapping
// them fills both pipes instead of running each at half machine utilization.
// Byte layouts of xt/wmod identical to the verified split kernels.
__global__ __launch_bounds__(256) void prep_fused(
    const float* __restrict__ fm, const float* __restrict__ w,
    const float* __restrict__ style, u16* __restrict__ xt,
    u16* __restrict__ wm, int b0)
{
  __shared__ __align__(16) char smraw[18448];     // union: 64*33 f32 | 4608+4 f32
  const int bid = blockIdx.x;
  const int g = bid / 3, rrole = bid - g * 3;
  const int tid = threadIdx.x;

  if (rrole < 2) {
    // ---------- transpose body (verified) ----------
    float* sm = (float*)smraw;                    // 64*33 floats
    const int ti = g * 2 + rrole;
    const int y = ti & 63, cg = (ti >> 6) & 15, bl = ti >> 10;
    const int x = tid & 63, cq = tid >> 6;
    const float* src = fm + (((size_t)(b0 + bl) * 512 + cg * 32) * 64 + y) * 64;
#pragma unroll
    for (int j = 0; j < 8; ++j) {
      int ci = j * 4 + cq;
      sm[x * 33 + ci] = src[(size_t)ci * 4096 + x];   // coalesced along x
    }

    u16* cgbase = xt + (size_t)(bl * 16 + cg) * XT_CGELEMS;
    const uint4 z = {0u, 0u, 0u, 0u};
    u16* rowb = cgbase + (size_t)(y + 1) * XT_ROWELEMS;
    if (tid < 4)              ((uint4*)rowb)[tid] = z;                  // col 0
    else if (tid < 8)         ((uint4*)(rowb + 65 * 32))[tid - 4] = z;  // col 65
    if (y == 0)  for (int i = tid; i < 264; i += 256) ((uint4*)cgbase)[i] = z;
    if (y == 63) for (int i = tid; i < 264; i += 256) ((uint4*)(cgbase + 65 * XT_ROWELEMS))[i] = z;

    __syncthreads();
    // interior cols 1..64: thread writes one 16B slot = channels (tid&3)*8..+7
    // of col 1+(tid>>2). Pre-swizzle: slot ^= (col>>1)&3.
    union { u16 s[8]; uint4 v; } u;
#pragma unroll
    for (int j = 0; j < 8; ++j) {
      int e = tid * 8 + j;                            // e = x*32 + c32
      u.s[j] = f2bf(sm[(e >> 5) * 33 + (e & 31)]);
    }
    const int col = 1 + (tid >> 2);
    const int slot = (tid & 3) ^ ((col >> 1) & 3);
    ((uint4*)rowb)[col * 4 + slot] = u.v;
  } else {
    // ---------- modulate body (verified, o512 layout) ----------
    float* sv = (float*)smraw;                    // 4608 floats
    float* red = (float*)(smraw + 18432);         // 4 floats
    const int o = g & 511, bl = g >> 9;
    const float gain = 0.014731391f;              // 1/sqrt(512*9)
    const float* wo = w + (size_t)o * 4608;       // flat idx = ci*9 + t
    const float* st = style + (size_t)(b0 + bl) * 512;
    float ss = 0.f;
#pragma unroll
    for (int j = 0; j < 18; ++j) {
      int idx = j * 256 + tid;
      float v = wo[idx] * gain * st[idx / 9];
      sv[idx] = v;
      ss += v * v;
    }
#pragma unroll
    for (int off = 32; off > 0; off >>= 1) ss += __shfl_down(ss, off, 64);
    if ((tid & 63) == 0) red[tid >> 6] = ss;
    __syncthreads();
    float sinv = rsqrtf(red[0] + red[1] + red[2] + red[3] + 1e-8f);
    const int axor = ((o >> 1) & 3) << 3;         // pre-swizzle for conv A-reads
    u16* base = wm + (size_t)bl * WM_ELEMS + (size_t)o * 32;
#pragma unroll
    for (int j = 0; j < 18; ++j) {
      int e = j * 256 + tid;                      // e = t*512 + c
      int t = e >> 9, c = e & 511;
      base[((size_t)(t * 16 + (c >> 5))) * 16384 + ((c & 31) ^ axor)] = f2bf(sv[c * 9 + t] * sinv);
    }
  }
}

// ---------------- kernel 3: implicit-GEMM conv via bf16 MFMA ----------------
// grid 64*nb linear, 256 threads. C tile 256x128 per block, K=4608.
// Wave tile 128x64 (8x4 frags): 12 ds_read_b128 per 32 MFMA (ratio 2.67) ->
// LDS-read no longer the binding resource. Proven m97-style sync discipline
// (stage next A async, __syncthreads per K-step drains DMA). Swizzled LDS
// reads (conflicts = 0, verified round 1). UNCHANGED from round 2 (159 us).
__global__ __launch_bounds__(256, 2) void conv_mfma(
    const u16* __restrict__ Wmod, const u16* __restrict__ xt,
    float* __restrict__ out, int b0, int nb)
{
  const int id = blockIdx.x;
  const int bl = id % nb;                           // same batch -> same XCD (round robin)
  const int rest = id / nb;
  const int og = rest & 1, p_blk = rest >> 1;       // og: 256-row M chunk
  const int tid = threadIdx.x;
  const int lane = tid & 63, wave = tid >> 6;
  const int wm_off = (wave & 1) * 128, wn_off = (wave >> 1) * 64;
  const int l15 = lane & 15, quad = lane >> 4;

  __shared__ __align__(16) u16 As[2][8192];         // 2 x 16 KB A k-slices (256 rows x 32)
  __shared__ __align__(16) u16 Bs[8448];            // [r4][col66][c32] = 16896 B

  const int y0 = p_blk * 2;
  const size_t xt_base = ((size_t)(bl * 16) * XT_CGELEMS) + (size_t)y0 * XT_ROWELEMS;
  const size_t w_base = (size_t)bl * WM_ELEMS + (size_t)og * (256 * 32);

  auto stage_b = [&](int cg) {                      // 16896 B contiguous, async
    const char* g = (const char*)(xt + xt_base + (size_t)cg * XT_CGELEMS);
    for (int r = wave; r < 16; r += 4)
      GLDS(g + r * 1024 + lane * 16, (char*)Bs + r * 1024);
    if (wave == 0 && lane < 32)                     // 512 B tail
      GLDS(g + 16384 + lane * 16, (char*)Bs + 16384);
  };
  auto stage_a = [&](int t, int cg, int buf) {      // 16 KB contiguous, async (4 GLDS/wave)
    const char* g = (const char*)(Wmod + w_base + (size_t)(t * 16 + cg) * 16384);
    for (int r = wave; r < 16; r += 4)
      GLDS(g + r * 1024 + lane * 16, (char*)As[buf] + r * 1024);
  };

  // loop-invariant swizzled fragment addresses
  int aoff[8];
#pragma unroll
  for (int mt = 0; mt < 8; ++mt) {
    int row = wm_off + mt * 16 + l15;               // local o-row; global o = og*256+row,
    aoff[mt] = row * 32 + ((quad ^ ((row >> 1) & 3)) << 3);  // same ((o>>1)&3) swizzle
  }
  int pr[4], pc[4];
#pragma unroll
  for (int nt = 0; nt < 4; ++nt) {
    int p = wn_off + nt * 16 + l15;
    pr[nt] = p >> 6; pc[nt] = p & 63;
  }

  floatx4 acc[8][4];
  const floatx4 zf = {0.f, 0.f, 0.f, 0.f};
#pragma unroll
  for (int mt = 0; mt < 8; ++mt)
#pragma unroll
    for (int nt = 0; nt < 4; ++nt) acc[mt][nt] = zf;

  stage_b(0);
  stage_a(0, 0, 0);
  __syncthreads();                                  // vmcnt drain -> data visible

#pragma unroll 1
  for (int cg = 0; cg < 16; ++cg) {
#pragma unroll 1
    for (int t = 0; t < 9; ++t) {
      const int cur = (cg * 9 + t) & 1, nxt = cur ^ 1;
      const bool last = (cg == 15 && t == 8);
      const bool cgb = (t == 8 && cg < 15);         // cg boundary
      if (!last) stage_a(t < 8 ? t + 1 : 0, t < 8 ? cg : cg + 1, nxt);  // async prefetch

      const int ky = t / 3, kx = t - ky * 3;
      s16x8 afr[8], bfr[4];
      const u16* Ab = As[cur];
#pragma unroll
      for (int nt = 0; nt < 4; ++nt) {              // B[n=lane&15][k=quad*8+j], swizzled
        int r = pr[nt] + ky, c = pc[nt] + kx;
        bfr[nt] = *(const s16x8*)&Bs[(r * 66 + c) * 32 + ((quad ^ ((c >> 1) & 3)) << 3)];
      }
#pragma unroll
      for (int mt = 0; mt < 8; ++mt)                // A[m=lane&15][k=quad*8+j], swizzled
        afr[mt] = *(const s16x8*)&Ab[aoff[mt]];
#pragma unroll
      for (int mt = 0; mt < 8; ++mt)
#pragma unroll
        for (int nt = 0; nt < 4; ++nt)
          acc[mt][nt] = __builtin_amdgcn_mfma_f32_16x16x32_bf16(
              afr[mt], bfr[nt], acc[mt][nt], 0, 0, 0);

      if (cgb) {
        __syncthreads();                            // all waves done reading Bs
        stage_b(cg + 1);                            // async restage
      }
      __syncthreads();                              // drains DMA; LDS visible
    }
  }

  // epilogue: C/D layout col=lane&15, row=quad*4+reg (m89-verified)
  float* outp = out + ((size_t)(b0 + bl) * 512 + og * 256) * 4096 + p_blk * 128;
#pragma unroll
  for (int mt = 0; mt < 8; ++mt)
#pragma unroll
    for (int nt = 0; nt < 4; ++nt) {
      int n = wn_off + nt * 16 + l15;
#pragma unroll
      for (int r = 0; r < 4; ++r) {
        int m = wm_off + mt * 16 + quad * 4 + r;
        outp[(size_t)m * 4096 + n] = acc[mt][nt][r];
      }
    }
}

// ---------------- fallback: zero-workspace direct conv (R6, known-PASS) ----------------
__global__ __launch_bounds__(256) void conv_direct(
    const float* __restrict__ fm, const float* __restrict__ style,
    const float* __restrict__ w, float* __restrict__ out)
{
  const int o = blockIdx.x, b = blockIdx.y, tid = threadIdx.x;
  __shared__ float swm[4608];
  __shared__ float red[4];
  const float gain = 0.014731391f;
  const float* wo = w + (size_t)o * 4608;
  const float* st = style + (size_t)b * 512;
  float ss = 0.f;
#pragma unroll
  for (int j = 0; j < 18; ++j) {
    int idx = j * 256 + tid;
    float v = wo[idx] * gain * st[idx / 9];
    swm[idx] = v;
    ss += v * v;
  }
#pragma unroll
  for (int off = 32; off > 0; off >>= 1) ss += __shfl_down(ss, off, 64);
  if ((tid & 63) == 0) red[tid >> 6] = ss;
  __syncthreads();
  const float sinv = rsqrtf(red[0] + red[1] + red[2] + red[3] + 1e-8f);

  const int y = tid >> 2, x0 = (tid & 3) * 16;
  float acc[16];
#pragma unroll
  for (int i = 0; i < 16; ++i) acc[i] = 0.f;
  const float* fb = fm + (size_t)b * 512 * 4096;
  for (int ci = 0; ci < 512; ++ci) {
    const float* fc = fb + (size_t)ci * 4096;
    const float* wr = swm + ci * 9;
#pragma unroll
    for (int ky = 0; ky < 3; ++ky) {
      int yy = y + ky - 1;
      if (yy < 0 || yy > 63) continue;
      const float* frow = fc + yy * 64;
#pragma unroll
      for (int kx = 0; kx < 3; ++kx) {
        float wv = wr[ky * 3 + kx];
#pragma unroll
        for (int i = 0; i < 16; ++i) {
          int xx = x0 + i + kx - 1;
          float xv = (xx >= 0 && xx < 64) ? frow[xx] : 0.f;
          acc[i] += wv * xv;
        }
      }
    }
  }
  float* op = out + ((size_t)b * 512 + o) * 4096 + y * 64 + x0;
#pragma unroll
  for (int i = 0; i < 16; ++i) op[i] = acc[i] * sinv;
}

extern "C" void kernel_launch(void* const* d_in, const int* in_sizes, int n_in,
                              void* d_out, int out_size, void* d_ws, size_t ws_size,
                              hipStream_t stream) {
  const float* fm = (const float*)d_in[0];     // (8,512,64,64) fp32
  const float* style = (const float*)d_in[1];  // (8,512) fp32
  const float* w = (const float*)d_in[2];      // (512,512,3,3) fp32
  float* out = (float*)d_out;                  // (8,512,64,64) fp32

  if (ws_size < XT_PB + WM_PB) {               // workspace too small: direct path
    conv_direct<<<dim3(512, 8), 256, 0, stream>>>(fm, style, w, out);
    return;
  }
  int nb = 8;
  while (nb > 1 && (size_t)nb * (XT_PB + WM_PB) > ws_size) nb >>= 1;

  u16* xt = (u16*)d_ws;
  u16* wmod = (u16*)((char*)d_ws + (size_t)nb * XT_PB);

  for (int b0 = 0; b0 < 8; b0 += nb) {
    prep_fused<<<dim3(1536 * nb), 256, 0, stream>>>(fm, w, style, xt, wmod, b0);
    conv_mfma<<<dim3(64 * nb), 256, 0, stream>>>(wmod, xt, out, b0, nb);
  }
}